// Round 4
// baseline (316.441 us; speedup 1.0000x reference)
//
#include <hip/hip_runtime.h>
#include <hip/hip_bf16.h>

// Problem constants: B=8, C=192, H=W=128, NH=6, HD=32, N=16384
constexpr int B   = 8;
constexpr int Cc  = 192;
constexpr int H   = 128;
constexpr int Wd  = 128;
constexpr int NH  = 6;
constexpr int HW  = H * Wd;       // 16384
constexpr int QKV = 3 * Cc;       // 576

typedef short s16x4 __attribute__((ext_vector_type(4)));
typedef short s16x8 __attribute__((ext_vector_type(8)));
typedef float f32x16 __attribute__((ext_vector_type(16)));

// Workspace layout (bytes):
//   qkv  : [B][576][HW] bf16                 = 150,994,944
//   part : [B][NH][8][1024] fp32 qk partials =   1,572,864
//   attn : [B][NH][32][32] fp32 (softmaxed)  =     196,608
//   ssq  : [2][B][Cc] fp32 (q then k)        =      12,288
//   M    : [B][192][192] bf16 ([o][c])       =     589,824
constexpr size_t OFF_QKV  = 0;
constexpr size_t OFF_PART = 150994944ULL;
constexpr size_t OFF_ATTN = OFF_PART + 1572864ULL;
constexpr size_t OFF_SSQ  = OFF_ATTN + 196608ULL;
constexpr size_t OFF_M    = OFF_SSQ + 12288ULL;
constexpr int    N_ZERO   = 12288 / 4;    // only ssq needs zeroing

__device__ inline unsigned short f2bf(float f) {
    __hip_bfloat16 h = __float2bfloat16(f);
    return *(unsigned short*)&h;
}

__global__ void zero_kernel(float* __restrict__ p, int n) {
    int i = blockIdx.x * 256 + threadIdx.x;
    if (i < n) p[i] = 0.f;
}

// ---------------------------------------------------------------------------
// K1: grouped 3x3 conv, groups=C, out=3C bf16. o = 3*g + j uses input ch g.
// LDS stages the 18x128 interior once (stride 132 floats: b128 reads/writes
// hit all 8 bank-quads -> conflict-free). x-halo from neighbor lanes via
// shfl; image boundary lanes forced to 0. ssq: wave shuffle-reduce + atomic.
// grid: (8 row-tiles, 192 groups, 8 batch), block 256 = 16 rows x 16 threads.
// ---------------------------------------------------------------------------
constexpr int TS = 16;

__global__ __launch_bounds__(256) void conv_qkv(
    const float* __restrict__ x, const float* __restrict__ w,
    const float* __restrict__ bias, unsigned short* __restrict__ qkv,
    float* __restrict__ ssq)
{
    int tile = blockIdx.x;
    int g    = blockIdx.y;
    int b    = blockIdx.z;
    int tid  = threadIdx.x;
    int y0   = tile * TS;

    __shared__ float smx[TS + 2][132];

    const float* xp = x + ((size_t)b * Cc + g) * HW;
    for (int i = tid; i < (TS + 2) * 32; i += 256) {
        int r = i >> 5, c4 = (i & 31) * 4;
        int y = y0 - 1 + r;
        float4 v4 = make_float4(0.f, 0.f, 0.f, 0.f);
        if (y >= 0 && y < H) v4 = *(const float4*)(xp + (size_t)y * Wd + c4);
        *(float4*)&smx[r][c4] = v4;
    }

    float wreg[3][9], breg[3];
    for (int j = 0; j < 3; ++j) {
        const float* wp = w + (size_t)(3 * g + j) * 9;
        for (int t = 0; t < 9; ++t) wreg[j][t] = wp[t];
        breg[j] = bias[3 * g + j];
    }
    __syncthreads();

    int yy = tid >> 4;        // 0..15 output row within tile
    int xi = tid & 15;        // 0..15, 8-wide x chunk
    int xq = xi * 8;

    float acc[3][8];
    for (int j = 0; j < 3; ++j)
        for (int xx = 0; xx < 8; ++xx) acc[j][xx] = breg[j];

    for (int dr = 0; dr < 3; ++dr) {
        float4 a4 = *(const float4*)&smx[yy + dr][xq];
        float4 b4 = *(const float4*)&smx[yy + dr][xq + 4];
        float l = __shfl_up(b4.w, 1);
        float rr = __shfl_down(a4.x, 1);
        float wd[10];
        wd[0] = (xi == 0) ? 0.f : l;
        wd[1] = a4.x; wd[2] = a4.y; wd[3] = a4.z; wd[4] = a4.w;
        wd[5] = b4.x; wd[6] = b4.y; wd[7] = b4.z; wd[8] = b4.w;
        wd[9] = (xi == 15) ? 0.f : rr;
        for (int j = 0; j < 3; ++j) {
            float w0 = wreg[j][dr * 3], w1 = wreg[j][dr * 3 + 1], w2 = wreg[j][dr * 3 + 2];
            for (int xx = 0; xx < 8; ++xx)
                acc[j][xx] += w0 * wd[xx] + w1 * wd[xx + 1] + w2 * wd[xx + 2];
        }
    }

    bool track = (g < 128);
    int y = y0 + yy;
    for (int j = 0; j < 3; ++j) {
        float ss = 0.f;
        unsigned short pk[8];
        for (int xx = 0; xx < 8; ++xx) {
            float s = acc[j][xx];
            ss += s * s;
            pk[xx] = f2bf(s);
        }
        unsigned short* op = qkv + ((size_t)b * QKV + 3 * g + j) * HW
                                 + (size_t)y * Wd + xq;
        uint4 uu;
        uu.x = (unsigned int)pk[0] | ((unsigned int)pk[1] << 16);
        uu.y = (unsigned int)pk[2] | ((unsigned int)pk[3] << 16);
        uu.z = (unsigned int)pk[4] | ((unsigned int)pk[5] << 16);
        uu.w = (unsigned int)pk[6] | ((unsigned int)pk[7] << 16);
        *(uint4*)op = uu;
        if (track) {
            for (int off = 1; off < 64; off <<= 1) ss += __shfl_xor(ss, off);
            if ((tid & 63) == 0) {
                int o = 3 * g + j;
                atomicAdd(&ssq[(o < Cc ? 0 : 1) * B * Cc + b * Cc + (o % Cc)], ss);
            }
        }
    }
}

// ---------------------------------------------------------------------------
// K2: qk partials via MFMA 32x32x16 with LDS-staged tiles. Block = (b,h,1/8
// of N). 8 chunks of 256n: stage q,k [32][256] bf16 (row stride 264 shorts,
// conflict-free), each wave MFMAs its 64-n quarter, accumulates in regs.
// Final: cross-wave LDS reduce -> non-atomic partial store.
// grid: (8, NH, B), block 256.
// ---------------------------------------------------------------------------
constexpr int NPART = 8;

__global__ __launch_bounds__(256) void qk_mfma(
    const unsigned short* __restrict__ qkv, float* __restrict__ part)
{
    int h = blockIdx.y, b = blockIdx.z;
    int tid = threadIdx.x;
    int wv = tid >> 6, lane = tid & 63;
    int col = lane & 31, half = lane >> 5;

    __shared__ unsigned short qs[32][264];
    __shared__ unsigned short ks[32][264];

    const unsigned short* qb = qkv + ((size_t)b * QKV + h * 32) * HW
                                   + (size_t)blockIdx.x * (HW / NPART);
    const unsigned short* kb = qb + (size_t)Cc * HW;

    f32x16 acc;
    for (int i = 0; i < 16; ++i) acc[i] = 0.f;

    for (int chunk = 0; chunk < 8; ++chunk) {
        int nc = chunk * 256;
        for (int it = 0; it < 8; ++it) {
            int idx = it * 256 + tid;
            int row = idx >> 5, ch = idx & 31;
            const unsigned short* src = (row < 32 ? qb + (size_t)row * HW
                                                  : kb + (size_t)(row - 32) * HW)
                                        + nc + ch * 8;
            uint4 d = *(const uint4*)src;
            unsigned short* dst = (row < 32) ? &qs[row][ch * 8] : &ks[row - 32][ch * 8];
            *(uint4*)dst = d;
        }
        __syncthreads();
        int koff = wv * 64 + half * 8;
        for (int t = 0; t < 4; ++t) {
            s16x8 a = *(const s16x8*)&qs[col][koff + t * 16];
            s16x8 bb = *(const s16x8*)&ks[col][koff + t * 16];
            acc = __builtin_amdgcn_mfma_f32_32x32x16_bf16(a, bb, acc, 0, 0, 0);
        }
        __syncthreads();
    }

    float* sred = (float*)&qs[0][0];   // 16 KB reuse (qs is 16896 B)
    for (int r = 0; r < 16; ++r) {
        int row = (r & 3) + 8 * (r >> 2) + 4 * half;
        sred[wv * 1024 + row * 32 + col] = acc[r];
    }
    __syncthreads();
    float* pp = part + (((size_t)(b * NH + h)) * NPART + blockIdx.x) * 1024;
    for (int i = tid; i < 1024; i += 256)
        pp[i] = sred[i] + sred[1024 + i] + sred[2048 + i] + sred[3072 + i];
}

// ---------------------------------------------------------------------------
// K2b: sum 8 partials, scale by 1/(||q_c|| ||k_d||) * temperature[h],
// softmax over d, write attn. grid: 48, block 64 (32 active rows).
// ---------------------------------------------------------------------------
__global__ void softmax_attn(const float* __restrict__ part,
                             float* __restrict__ attn,
                             const float* __restrict__ ssq,
                             const float* __restrict__ temp)
{
    int h = blockIdx.x % NH, b = blockIdx.x / NH;
    __shared__ float nk[32];
    if (threadIdx.x < 32)
        nk[threadIdx.x] = fmaxf(sqrtf(ssq[B * Cc + b * Cc + h * 32 + threadIdx.x]), 1e-12f);
    __syncthreads();
    int c = threadIdx.x;
    if (c >= 32) return;
    float nq = fmaxf(sqrtf(ssq[b * Cc + h * 32 + c]), 1e-12f);
    float t = temp[h];
    const float* pp = part + (size_t)(b * NH + h) * (NPART * 1024) + c * 32;
    float row[32];
    float mx = -1e30f;
    for (int d = 0; d < 32; ++d) {
        float v = 0.f;
        for (int p = 0; p < NPART; ++p) v += pp[p * 1024 + d];
        v = v / (nq * nk[d]) * t;
        row[d] = v;
        mx = fmaxf(mx, v);
    }
    float sum = 0.f;
    for (int d = 0; d < 32; ++d) { row[d] = expf(row[d] - mx); sum += row[d]; }
    float inv = 1.f / sum;
    float* ap = attn + ((size_t)(b * NH + h) * 32 + c) * 32;
    for (int d = 0; d < 32; ++d) ap[d] = row[d] * inv;
}

// ---------------------------------------------------------------------------
// K3a: M[b][o][c=h*32+d] = sum_{c'} w_out[o][h*32+c'] * attn[b][h][c'][d], bf16.
// ---------------------------------------------------------------------------
__global__ __launch_bounds__(256) void make_m(
    const float* __restrict__ attn, const float* __restrict__ w_out,
    unsigned short* __restrict__ M)
{
    int h = blockIdx.x, b = blockIdx.y;
    __shared__ float as[32][33];
    for (int i = threadIdx.x; i < 1024; i += 256)
        as[i / 32][i % 32] = attn[(size_t)((b * NH + h) * 32 + i / 32) * 32 + i % 32];
    __syncthreads();
    for (int i = threadIdx.x; i < Cc * 32; i += 256) {
        int o = i / 32, d = i % 32;
        const float* wp = w_out + (size_t)o * Cc + h * 32;
        float s = 0.f;
        for (int cp = 0; cp < 32; ++cp) s += wp[cp] * as[cp][d];
        M[((size_t)b * Cc + o) * Cc + h * 32 + d] = f2bf(s);
    }
}

// ---------------------------------------------------------------------------
// K3b: out[b][o][n] = sum_c M[o][c] * v[c][n] + b_out[o] via MFMA 32x32x16.
// Per-wave autonomous: wave tile 192o x 32n, no __syncthreads. Each wave
// stages its own 16c x 32n v-transpose in a private LDS region.
// grid: (128, 8), block 256.
// ---------------------------------------------------------------------------
constexpr int BN = 128;

__global__ __launch_bounds__(256) void out_gemm(
    const unsigned short* __restrict__ M, const unsigned short* __restrict__ qkv,
    const float* __restrict__ b_out, float* __restrict__ out)
{
    int tid  = threadIdx.x;
    int wv   = tid >> 6, lane = tid & 63;
    int b    = blockIdx.y;
    int n0   = blockIdx.x * BN + wv * 32;
    int col  = lane & 31, half = lane >> 5;
    int a    = lane >> 3;
    int bq   = lane & 7;

    __shared__ unsigned short vsT[4][32][20];
    unsigned short (*vt)[20] = vsT[wv];

    const unsigned short* vp = qkv + ((size_t)b * QKV + 2 * Cc) * HW + n0 + 4 * bq;
    const unsigned short* mp = M + (size_t)b * Cc * Cc;

    f32x16 acc[6];
    for (int t = 0; t < 6; ++t)
        for (int i = 0; i < 16; ++i) acc[t][i] = 0.f;

    const unsigned short* s0 = vp + (size_t)(2 * a) * HW;
    ushort4 va = *(const ushort4*)s0;
    ushort4 vb = *(const ushort4*)(s0 + HW);

    for (int k0 = 0; k0 < Cc; k0 += 16) {
        *(unsigned int*)&vt[4 * bq + 0][2 * a] = (unsigned int)va.x | ((unsigned int)vb.x << 16);
        *(unsigned int*)&vt[4 * bq + 1][2 * a] = (unsigned int)va.y | ((unsigned int)vb.y << 16);
        *(unsigned int*)&vt[4 * bq + 2][2 * a] = (unsigned int)va.z | ((unsigned int)vb.z << 16);
        *(unsigned int*)&vt[4 * bq + 3][2 * a] = (unsigned int)va.w | ((unsigned int)vb.w << 16);
        if (k0 + 16 < Cc) {
            const unsigned short* s1 = vp + (size_t)(k0 + 16 + 2 * a) * HW;
            va = *(const ushort4*)s1;
            vb = *(const ushort4*)(s1 + HW);
        }
        __builtin_amdgcn_wave_barrier();
        s16x4 lo = *(const s16x4*)&vt[col][half * 8];
        s16x4 hi = *(const s16x4*)&vt[col][half * 8 + 4];
        s16x8 bf = __builtin_shufflevector(lo, hi, 0, 1, 2, 3, 4, 5, 6, 7);
        for (int mt = 0; mt < 6; ++mt) {
            s16x8 af = *(const s16x8*)(mp + (size_t)(mt * 32 + col) * Cc + k0 + half * 8);
            acc[mt] = __builtin_amdgcn_mfma_f32_32x32x16_bf16(af, bf, acc[mt], 0, 0, 0);
        }
        __builtin_amdgcn_wave_barrier();
    }

    for (int mt = 0; mt < 6; ++mt) {
        f32x16 c = acc[mt];
        for (int rr = 0; rr < 16; ++rr) {
            int row = (rr & 3) + 8 * (rr >> 2) + 4 * half;
            int o = mt * 32 + row;
            out[((size_t)b * Cc + o) * HW + n0 + col] = c[rr] + b_out[o];
        }
    }
}

extern "C" void kernel_launch(void* const* d_in, const int* in_sizes, int n_in,
                              void* d_out, int out_size, void* d_ws, size_t ws_size,
                              hipStream_t stream) {
    const float* x      = (const float*)d_in[0];
    const float* w_qkv  = (const float*)d_in[1];
    const float* b_qkv  = (const float*)d_in[2];
    const float* temp   = (const float*)d_in[3];
    const float* w_out  = (const float*)d_in[4];
    const float* b_out  = (const float*)d_in[5];
    float* out = (float*)d_out;

    char* ws = (char*)d_ws;
    unsigned short* qkv = (unsigned short*)(ws + OFF_QKV);
    float* part         = (float*)(ws + OFF_PART);
    float* attn         = (float*)(ws + OFF_ATTN);
    float* ssq          = (float*)(ws + OFF_SSQ);
    unsigned short* M   = (unsigned short*)(ws + OFF_M);

    zero_kernel<<<(N_ZERO + 255) / 256, 256, 0, stream>>>(ssq, N_ZERO);
    conv_qkv<<<dim3(H / TS, Cc, B), 256, 0, stream>>>(x, w_qkv, b_qkv, qkv, ssq);
    qk_mfma<<<dim3(NPART, NH, B), 256, 0, stream>>>(qkv, part);
    softmax_attn<<<B * NH, 64, 0, stream>>>(part, attn, ssq, temp);
    make_m<<<dim3(NH, B), 256, 0, stream>>>(attn, w_out, M);
    out_gemm<<<dim3(HW / BN, B), 256, 0, stream>>>(M, qkv, b_out, out);
}